// Round 3
// baseline (392.868 us; speedup 1.0000x reference)
//
#include <hip/hip_runtime.h>

// CubicSplineUpsampling: (2,3,96,96,96) f32 -> (2,3,192,192,192) f32.
//
// out_line(192) = M * in_line(96) per axis, M = U_clamped(192x96) . W(96x96),
// banded to 28 taps at j0=c-13 (truncation ~1e-8 relative).
//
// R3: line passes (Y/X) restructured from fat sliding-window threads
// (39-reg window, 4B loads, serial chunk refills -> latency-bound at
// 1.37 TB/s effective) to thin gather threads: thread = (o, c, float4 col),
// 28 INDEPENDENT float4 window loads up-front (full MLP), exact weights
// from LDS, 224 FMA, 2 float4 stores. Block = 48c x 8cols: wave loads are
// 128B contiguous segments; block input slab ~9KB -> L1-resident, so the
// 14x j-overlap across c is absorbed by L1 (HBM traffic stays 1x).
// pass_z kept IDENTICAL to R2 as the control variable.

#define TAPS 28
#define CHUNK 12
#define WIN (CHUNK + TAPS - 1)  // 39

__device__ double g_Wd[96 * 96];
__device__ float g_Mb[192 * TAPS];            // [i][t] row-major
__device__ float g_bufA[6 * 96 * 96 * 192];   // after Z pass
__device__ float g_bufB[6 * 96 * 192 * 192];  // after Y pass

__device__ __forceinline__ int clamp96(int j) { return j < 0 ? 0 : (j > 95 ? 95 : j); }

__global__ void compute_Wd_kernel(double* __restrict__ Wd) {
    int j = threadIdx.x;
    if (j >= 96) return;
    const double p = -0.26794919243112270647253365849413;  // sqrt(3)-2
    double c[96];
    double pj = 1.0;
    for (int t = 0; t < j; ++t) pj *= p;
    double p191j = 1.0;
    for (int t = 0; t < 191 - j; ++t) p191j *= p;
    double p2n = 1.0;
    for (int t = 0; t < 192; ++t) p2n *= p;
    double K = p / (1.0 - p2n);
    double cur = 6.0 * K * (pj + p191j) + (j == 0 ? 6.0 : 0.0);
    c[0] = cur;
    for (int i = 1; i < 96; ++i) {
        cur = (i == j ? 6.0 : 0.0) + p * cur;
        c[i] = cur;
    }
    double nxt = cur * (p / (p - 1.0));
    Wd[95 * 96 + j] = nxt;
    for (int i = 94; i >= 0; --i) {
        nxt = p * (nxt - c[i]);
        Wd[i * 96 + j] = nxt;
    }
}

__global__ void compute_M_kernel(const double* __restrict__ Wd, float* __restrict__ Mb) {
    int i = threadIdx.x;
    if (i >= 192) return;
    const double cw[8] = {1.0 / 384.0, 121.0 / 384.0, 235.0 / 384.0, 27.0 / 384.0,
                          27.0 / 384.0, 235.0 / 384.0, 121.0 / 384.0, 1.0 / 384.0};
    int ph = i & 1;
    int c = i >> 1;
    for (int t = 0; t < TAPS; ++t) {
        int j = c - 13 + t;
        double m = 0.0;
        if (j >= 0 && j < 96) {
            for (int tt = 0; tt < 4; ++tt) {
                int k = c + ph - 2 + tt;
                k = k < 0 ? 0 : (k > 95 ? 95 : k);
                m += cw[ph * 4 + tt] * Wd[k * 96 + j];
            }
        }
        Mb[i * TAPS + t] = (float)m;
    }
}

// Z pass: lines contiguous along z. Block: 64 lines staged in padded LDS.
// 512 threads: wave w (of 8) computes c in [12w, 12w+12) for all 64 lines
// (lane = line). Waves 1..6 are interior -> SGPR-stencil FMA only.
// (UNCHANGED from R2 — control variable for this round.)
__global__ __launch_bounds__(512) void pass_z(const float* __restrict__ in,
                                              float* __restrict__ out,
                                              const float* __restrict__ Mb) {
    __shared__ float s_in[64 * 97];
    __shared__ float s_out[64 * 193];
    float w0[TAPS], w1[TAPS];
#pragma unroll
    for (int t = 0; t < TAPS; ++t) {
        w0[t] = Mb[96 * TAPS + t];
        w1[t] = Mb[97 * TAPS + t];
    }
    size_t base = (size_t)blockIdx.x * 64;
    const float* src = in + base * 96;
    int tid = threadIdx.x;
    for (int k = tid; k < 64 * 96; k += 512)
        s_in[(k / 96) * 97 + (k % 96)] = src[k];
    __syncthreads();

    int lane = tid & 63;
    int wave = tid >> 6;
    int c0 = wave * CHUNK;
    const float* xl = s_in + lane * 97;
    float* op = s_out + lane * 193 + 2 * c0;
    float win[WIN];
#pragma unroll
    for (int k = 0; k < WIN; ++k) win[k] = xl[clamp96(c0 - 13 + k)];

    if (c0 >= 12 && c0 + CHUNK <= 84) {  // interior: pure register FMA
#pragma unroll
        for (int mi = 0; mi < CHUNK; ++mi) {
            float a0 = 0.f, a1 = 0.f;
#pragma unroll
            for (int t = 0; t < TAPS; ++t) {
                float xv = win[mi + t];
                a0 = fmaf(w0[t], xv, a0);
                a1 = fmaf(w1[t], xv, a1);
            }
            op[2 * mi] = a0;
            op[2 * mi + 1] = a1;
        }
    } else {  // boundary: per-m table rows
#pragma unroll
        for (int mi = 0; mi < CHUNK; ++mi) {
            int m = c0 + mi;
            int wb = __builtin_amdgcn_readfirstlane(m * 2 * TAPS);
            const float* wr = Mb + wb;
            float a0 = 0.f, a1 = 0.f;
#pragma unroll
            for (int t = 0; t < TAPS; ++t) {
                float xv = win[mi + t];
                a0 = fmaf(wr[t], xv, a0);
                a1 = fmaf(wr[TAPS + t], xv, a1);
            }
            op[2 * mi] = a0;
            op[2 * mi + 1] = a1;
        }
    }
    __syncthreads();
    float* dst = out + base * 192;
    for (int k = tid; k < 64 * 192; k += 512)
        dst[k] = s_out[(k / 192) * 193 + (k % 192)];
}

// Y/X gather pass: in [O][96][INNER] -> out [O][192][INNER].
// Thread = (o, c, r4): 28 independent float4 window loads (stride INNER),
// exact weights from LDS, 224 FMA, stores out rows 2c and 2c+1 as float4.
// Block = 48 c x 8 r4-cols (384 thr): wave-loads = 128B contiguous segments;
// input slab per block ~(48+27) rows x 8 cols x 16B = 9.4KB -> L1-resident,
// j-overlap across c absorbed by L1 (unique HBM traffic ~1x).
template <int INNER>
__global__ __launch_bounds__(384) void pass_gather(const float* __restrict__ in,
                                                   float* __restrict__ out,
                                                   const float* __restrict__ Mb) {
    constexpr int TILES = INNER / 32;  // r4-tiles of 8 float4 (32 floats)
    constexpr int IV = INNER / 4;
    __shared__ float s_w[192 * TAPS];  // 21.5 KB, exact banded weights
    int tid = threadIdx.x;
    {
        const float4* mb4 = (const float4*)Mb;
        float4* sw4 = (float4*)s_w;
        for (int k = tid; k < 192 * TAPS / 4; k += 384) sw4[k] = mb4[k];
    }
    __syncthreads();

    int cb = blockIdx.x & 1;          // c half: [0,48) or [48,96)
    int bi = blockIdx.x >> 1;
    int rt = bi % TILES;
    int o = bi / TILES;
    int c = cb * 48 + (tid >> 3);
    int r4 = rt * 8 + (tid & 7);

    const float4* src = (const float4*)(in + (size_t)o * 96 * INNER) + r4;
    float4* dst = (float4*)(out + (size_t)o * 192 * INNER) + r4;

    float4 xv[TAPS];
#pragma unroll
    for (int t = 0; t < TAPS; ++t)
        xv[t] = src[(size_t)clamp96(c - 13 + t) * IV];

    const float* w0 = s_w + 2 * c * TAPS;  // row 2c; row 2c+1 at +TAPS
    float4 a0 = make_float4(0.f, 0.f, 0.f, 0.f);
    float4 a1 = make_float4(0.f, 0.f, 0.f, 0.f);
#pragma unroll
    for (int t = 0; t < TAPS; ++t) {
        float4 x = xv[t];
        float b0 = w0[t];
        float b1 = w0[TAPS + t];
        a0.x = fmaf(b0, x.x, a0.x);
        a0.y = fmaf(b0, x.y, a0.y);
        a0.z = fmaf(b0, x.z, a0.z);
        a0.w = fmaf(b0, x.w, a0.w);
        a1.x = fmaf(b1, x.x, a1.x);
        a1.y = fmaf(b1, x.y, a1.y);
        a1.z = fmaf(b1, x.z, a1.z);
        a1.w = fmaf(b1, x.w, a1.w);
    }
    dst[(size_t)(2 * c) * IV] = a0;
    dst[(size_t)(2 * c + 1) * IV] = a1;
}

extern "C" void kernel_launch(void* const* d_in, const int* in_sizes, int n_in,
                              void* d_out, int out_size, void* d_ws, size_t ws_size,
                              hipStream_t stream) {
    const float* x = (const float*)d_in[0];
    float* out = (float*)d_out;
    double* Wd;
    float *Mb, *bufA, *bufB;
    hipGetSymbolAddress((void**)&Wd, HIP_SYMBOL(g_Wd));
    hipGetSymbolAddress((void**)&Mb, HIP_SYMBOL(g_Mb));
    hipGetSymbolAddress((void**)&bufA, HIP_SYMBOL(g_bufA));
    hipGetSymbolAddress((void**)&bufB, HIP_SYMBOL(g_bufB));

    compute_Wd_kernel<<<1, 96, 0, stream>>>(Wd);
    compute_M_kernel<<<1, 192, 0, stream>>>(Wd, Mb);

    // Z: 6*96*96 = 55296 lines / 64 per block, 512 threads (8 waves x 12-c)
    pass_z<<<864, 512, 0, stream>>>(x, bufA, Mb);
    // Y: O = 6*96 = 576, TILES = 192/32 = 6, x2 c-halves -> 6912 blocks
    pass_gather<192><<<576 * 6 * 2, 384, 0, stream>>>(bufA, bufB, Mb);
    // X: O = 6, TILES = 36864/32 = 1152, x2 c-halves -> 13824 blocks
    pass_gather<36864><<<6 * 1152 * 2, 384, 0, stream>>>(bufB, out, Mb);
}

// Round 4
// 331.988 us; speedup vs baseline: 1.1834x; 1.1834x over previous
//
#include <hip/hip_runtime.h>

// CubicSplineUpsampling: (2,3,96,96,96) f32 -> (2,3,192,192,192) f32.
//
// out_line(192) = M * in_line(96) per axis, M = U_clamped(192x96) . W(96x96),
// banded to 28 taps at j0=c-13 (truncation ~1e-8 relative).
//
// R4: Y/X passes = LDS-staged line transform. R3's gather was latency-bound:
// VGPR_Count=36 proved the compiler kept only ~4-6 of the 28 "independent"
// loads in flight -> 2.39 TB/s. Fix: block-level MLP. Block = (o, 64-col
// tile): stage full 96x64 slab into 24KB LDS (1536 independent float4 loads
// across 256 threads, each element fetched EXACTLY once -> no halo overfetch),
// then 4 waves x 24 c's compute from LDS (conflict-free: fixed row, lanes =
// consecutive cols), 51-reg window, 24x56 FMA, wave-wide 256B stores direct
// to global. Interior waves: SGPR Toeplitz stencil (rows 96/97, error <=1e-4
// << tol 1.56e-2, validated R2/R3 absmax). Edge waves: exact table rows.
// pass_z byte-identical (control).

#define TAPS 28
#define CHUNK 12
#define WIN (CHUNK + TAPS - 1)  // 39 (pass_z only)

__device__ double g_Wd[96 * 96];
__device__ float g_Mb[192 * TAPS];            // [i][t] row-major
__device__ float g_bufA[6 * 96 * 96 * 192];   // after Z pass
__device__ float g_bufB[6 * 96 * 192 * 192];  // after Y pass

__device__ __forceinline__ int clamp96(int j) { return j < 0 ? 0 : (j > 95 ? 95 : j); }

__global__ void compute_Wd_kernel(double* __restrict__ Wd) {
    int j = threadIdx.x;
    if (j >= 96) return;
    const double p = -0.26794919243112270647253365849413;  // sqrt(3)-2
    double c[96];
    double pj = 1.0;
    for (int t = 0; t < j; ++t) pj *= p;
    double p191j = 1.0;
    for (int t = 0; t < 191 - j; ++t) p191j *= p;
    double p2n = 1.0;
    for (int t = 0; t < 192; ++t) p2n *= p;
    double K = p / (1.0 - p2n);
    double cur = 6.0 * K * (pj + p191j) + (j == 0 ? 6.0 : 0.0);
    c[0] = cur;
    for (int i = 1; i < 96; ++i) {
        cur = (i == j ? 6.0 : 0.0) + p * cur;
        c[i] = cur;
    }
    double nxt = cur * (p / (p - 1.0));
    Wd[95 * 96 + j] = nxt;
    for (int i = 94; i >= 0; --i) {
        nxt = p * (nxt - c[i]);
        Wd[i * 96 + j] = nxt;
    }
}

__global__ void compute_M_kernel(const double* __restrict__ Wd, float* __restrict__ Mb) {
    int i = threadIdx.x;
    if (i >= 192) return;
    const double cw[8] = {1.0 / 384.0, 121.0 / 384.0, 235.0 / 384.0, 27.0 / 384.0,
                          27.0 / 384.0, 235.0 / 384.0, 121.0 / 384.0, 1.0 / 384.0};
    int ph = i & 1;
    int c = i >> 1;
    for (int t = 0; t < TAPS; ++t) {
        int j = c - 13 + t;
        double m = 0.0;
        if (j >= 0 && j < 96) {
            for (int tt = 0; tt < 4; ++tt) {
                int k = c + ph - 2 + tt;
                k = k < 0 ? 0 : (k > 95 ? 95 : k);
                m += cw[ph * 4 + tt] * Wd[k * 96 + j];
            }
        }
        Mb[i * TAPS + t] = (float)m;
    }
}

// Z pass (UNCHANGED from R2/R3 — control variable).
__global__ __launch_bounds__(512) void pass_z(const float* __restrict__ in,
                                              float* __restrict__ out,
                                              const float* __restrict__ Mb) {
    __shared__ float s_in[64 * 97];
    __shared__ float s_out[64 * 193];
    float w0[TAPS], w1[TAPS];
#pragma unroll
    for (int t = 0; t < TAPS; ++t) {
        w0[t] = Mb[96 * TAPS + t];
        w1[t] = Mb[97 * TAPS + t];
    }
    size_t base = (size_t)blockIdx.x * 64;
    const float* src = in + base * 96;
    int tid = threadIdx.x;
    for (int k = tid; k < 64 * 96; k += 512)
        s_in[(k / 96) * 97 + (k % 96)] = src[k];
    __syncthreads();

    int lane = tid & 63;
    int wave = tid >> 6;
    int c0 = wave * CHUNK;
    const float* xl = s_in + lane * 97;
    float* op = s_out + lane * 193 + 2 * c0;
    float win[WIN];
#pragma unroll
    for (int k = 0; k < WIN; ++k) win[k] = xl[clamp96(c0 - 13 + k)];

    if (c0 >= 12 && c0 + CHUNK <= 84) {
#pragma unroll
        for (int mi = 0; mi < CHUNK; ++mi) {
            float a0 = 0.f, a1 = 0.f;
#pragma unroll
            for (int t = 0; t < TAPS; ++t) {
                float xv = win[mi + t];
                a0 = fmaf(w0[t], xv, a0);
                a1 = fmaf(w1[t], xv, a1);
            }
            op[2 * mi] = a0;
            op[2 * mi + 1] = a1;
        }
    } else {
#pragma unroll
        for (int mi = 0; mi < CHUNK; ++mi) {
            int m = c0 + mi;
            int wb = __builtin_amdgcn_readfirstlane(m * 2 * TAPS);
            const float* wr = Mb + wb;
            float a0 = 0.f, a1 = 0.f;
#pragma unroll
            for (int t = 0; t < TAPS; ++t) {
                float xv = win[mi + t];
                a0 = fmaf(wr[t], xv, a0);
                a1 = fmaf(wr[TAPS + t], xv, a1);
            }
            op[2 * mi] = a0;
            op[2 * mi + 1] = a1;
        }
    }
    __syncthreads();
    float* dst = out + base * 192;
    for (int k = tid; k < 64 * 192; k += 512)
        dst[k] = s_out[(k / 192) * 193 + (k % 192)];
}

// Y/X staged pass: in [O][96][INNER] -> out [O][192][INNER].
// Block = (o, 64-col tile). Stage 96x64 slab (24KB LDS) via 1536 independent
// float4 loads; 4 waves x 24 c's x 64 cols compute from LDS; direct 256B
// wave-wide stores. Each input element fetched exactly once (no halo).
template <int INNER>
__global__ __launch_bounds__(256) void pass_staged(const float* __restrict__ in,
                                                   float* __restrict__ out,
                                                   const float* __restrict__ Mb) {
    constexpr int CT = INNER / 64;
    __shared__ float s[96 * 64];  // 24 KB, no pad needed (row-major, lane=col)
    int tid = threadIdx.x;
    int ct = blockIdx.x % CT;
    int o = blockIdx.x / CT;
    const float* src = in + (size_t)o * 96 * INNER + (size_t)ct * 64;
    float* dst = out + (size_t)o * 192 * INNER + (size_t)ct * 64;

    // Stage: 1536 float4s, 6 per thread, all independent.
#pragma unroll
    for (int it = 0; it < 6; ++it) {
        int k = tid + it * 256;
        int row = k >> 4;       // 0..95
        int c4 = k & 15;        // float4 index within 64-col row
        float4 v = *(const float4*)(src + (size_t)row * INNER + c4 * 4);
        *(float4*)(&s[row * 64 + c4 * 4]) = v;
    }
    __syncthreads();

    int col = tid & 63;
    int cq = tid >> 6;   // wave id 0..3, wave-uniform c range
    int c0 = cq * 24;

    float win[51];  // rows c0-13 .. c0+37 (clamped), this col
#pragma unroll
    for (int k = 0; k < 51; ++k) win[k] = s[clamp96(c0 - 13 + k) * 64 + col];

    if (cq == 1 || cq == 2) {  // interior c in [24,72): SGPR Toeplitz stencil
        float w0[TAPS], w1[TAPS];
#pragma unroll
        for (int t = 0; t < TAPS; ++t) {
            w0[t] = Mb[96 * TAPS + t];
            w1[t] = Mb[97 * TAPS + t];
        }
#pragma unroll
        for (int mi = 0; mi < 24; ++mi) {
            float a0 = 0.f, a1 = 0.f;
#pragma unroll
            for (int t = 0; t < TAPS; ++t) {
                float xv = win[mi + t];
                a0 = fmaf(w0[t], xv, a0);
                a1 = fmaf(w1[t], xv, a1);
            }
            int m = c0 + mi;
            dst[(size_t)(2 * m) * INNER + col] = a0;
            dst[(size_t)(2 * m + 1) * INNER + col] = a1;
        }
    } else {  // edge waves (c in [0,24) u [72,96)): exact table rows
#pragma unroll
        for (int mi = 0; mi < 24; ++mi) {
            int m = c0 + mi;
            int wb = __builtin_amdgcn_readfirstlane(m * 2 * TAPS);
            const float* wr = Mb + wb;
            float a0 = 0.f, a1 = 0.f;
#pragma unroll
            for (int t = 0; t < TAPS; ++t) {
                float xv = win[mi + t];
                a0 = fmaf(wr[t], xv, a0);
                a1 = fmaf(wr[TAPS + t], xv, a1);
            }
            dst[(size_t)(2 * m) * INNER + col] = a0;
            dst[(size_t)(2 * m + 1) * INNER + col] = a1;
        }
    }
}

extern "C" void kernel_launch(void* const* d_in, const int* in_sizes, int n_in,
                              void* d_out, int out_size, void* d_ws, size_t ws_size,
                              hipStream_t stream) {
    const float* x = (const float*)d_in[0];
    float* out = (float*)d_out;
    double* Wd;
    float *Mb, *bufA, *bufB;
    hipGetSymbolAddress((void**)&Wd, HIP_SYMBOL(g_Wd));
    hipGetSymbolAddress((void**)&Mb, HIP_SYMBOL(g_Mb));
    hipGetSymbolAddress((void**)&bufA, HIP_SYMBOL(g_bufA));
    hipGetSymbolAddress((void**)&bufB, HIP_SYMBOL(g_bufB));

    compute_Wd_kernel<<<1, 96, 0, stream>>>(Wd);
    compute_M_kernel<<<1, 192, 0, stream>>>(Wd, Mb);

    // Z: 6*96*96 = 55296 lines / 64 per block, 512 threads (8 waves x 12-c)
    pass_z<<<864, 512, 0, stream>>>(x, bufA, Mb);
    // Y: O = 6*96 = 576, CT = 192/64 = 3 -> 1728 blocks
    pass_staged<192><<<1728, 256, 0, stream>>>(bufA, bufB, Mb);
    // X: O = 6, CT = 36864/64 = 576 -> 3456 blocks
    pass_staged<36864><<<3456, 256, 0, stream>>>(bufB, out, Mb);
}